// Round 4
// baseline (408.552 us; speedup 1.0000x reference)
//
#include <hip/hip_runtime.h>

#define S_DIM 128
#define I_DIM 384
#define IN_DIM 256
#define PD 32
#define ODIM 128

typedef __attribute__((ext_vector_type(8))) __bf16 bf16x8;
typedef __attribute__((ext_vector_type(4))) float f32x4;

#define MFMA16(a, b, c) __builtin_amdgcn_mfma_f32_16x16x32_bf16((a), (b), (c), 0, 0, 0)

__device__ inline unsigned short f2bf(float f) {
    unsigned int u = __builtin_bit_cast(unsigned int, f);
    unsigned int r = (u + 0x7FFFu + ((u >> 16) & 1u)) >> 16;
    return (unsigned short)r;
}

// ---------------- prep: cast/transpose weights to bf16 ----------------
// WpT[f][k] = Wp[k][f]  (64 x 256)
// W2s fragment-order: idx = ((k0*128 + f)*4 + q)*8 + j, where k = k0*32+q*8+j = e*32+d
__global__ void prep_cast(const float* __restrict__ Wp, const float* __restrict__ W2,
                          unsigned short* __restrict__ WpT, unsigned short* __restrict__ W2s) {
    int t = blockIdx.x * 256 + threadIdx.x;
    if (t < 64 * 256) {
        int f = t >> 8, k = t & 255;
        WpT[t] = f2bf(Wp[k * 64 + f]);
    }
    if (t < 128 * 1024) {
        int j = t & 7, q = (t >> 3) & 3, f = (t >> 5) & 127, k0 = t >> 12;
        int k = k0 * 32 + q * 8 + j;
        int e = k >> 5, d = k & 31;
        W2s[t] = f2bf(W2[(d * 32 + e) * 128 + f]);
    }
}

// ---------------- norm: gram of mask -> store INVERSE ----------------
__global__ void norm_kernel(const float* __restrict__ mask, float* __restrict__ invn) {
    __shared__ float mi[S_DIM][16];
    __shared__ float mj[S_DIM][16];
    int t = threadIdx.x;
    int i0 = blockIdx.y * 16, j0 = blockIdx.x * 16;
    for (int p = 0; p < 8; ++p) {
        int s = p * 16 + (t >> 4);
        int c = t & 15;
        mi[s][c] = mask[s * I_DIM + i0 + c];
        mj[s][c] = mask[s * I_DIM + j0 + c];
    }
    __syncthreads();
    int ii = t >> 4, jj = t & 15;
    float acc = 0.f;
#pragma unroll 8
    for (int s = 0; s < S_DIM; ++s) acc += mi[s][ii] * mj[s][jj];
    invn[(i0 + ii) * I_DIM + (j0 + jj)] = 1.0f / (acc + 0.001f);
}

// ---------------- LN + projection (bf16 MFMA), i-major for coalesced T-store ----
__global__ __launch_bounds__(256, 2) void ln_proj(const float* __restrict__ x,
                                                  const float* __restrict__ mask,
                                                  const float* __restrict__ bias,
                                                  const unsigned short* __restrict__ WpT_g,
                                                  unsigned short* __restrict__ lT,
                                                  unsigned short* __restrict__ rT) {
    __shared__ unsigned short xsh[64 * 264];
    __shared__ unsigned short wpT[64 * 264];
    int t = threadIdx.x;
    int w = t >> 6, lane = t & 63;
    int i = blockIdx.x >> 1;
    int s0 = (blockIdx.x & 1) * 64;

    {
        int f = t >> 2, kq = (t & 3) * 64;
#pragma unroll
        for (int p = 0; p < 8; ++p) {
            int k = kq + p * 8;
            *(uint4*)&wpT[f * 264 + k] = *(const uint4*)&WpT_g[f * 256 + k];
        }
    }

    float4 vbuf[4];
#pragma unroll
    for (int p = 0; p < 4; ++p)
        vbuf[p] = *(const float4*)(x + ((size_t)(s0 + w * 16 + p) * I_DIM + i) * IN_DIM + lane * 4);

    for (int it = 0; it < 16; ++it) {
        float4 v = vbuf[it & 3];
        if (it + 4 < 16)
            vbuf[it & 3] = *(const float4*)(x + ((size_t)(s0 + w * 16 + it + 4) * I_DIM + i) * IN_DIM + lane * 4);
        float s1 = v.x + v.y + v.z + v.w;
        float s2 = v.x * v.x + v.y * v.y + v.z * v.z + v.w * v.w;
#pragma unroll
        for (int off = 32; off >= 1; off >>= 1) {
            s1 += __shfl_xor(s1, off);
            s2 += __shfl_xor(s2, off);
        }
        float mu = s1 * (1.f / 256.f);
        float var = s2 * (1.f / 256.f) - mu * mu;
        float rs = rsqrtf(var + 1e-5f);
        unsigned int h0 = f2bf((v.x - mu) * rs);
        unsigned int h1 = f2bf((v.y - mu) * rs);
        unsigned int h2 = f2bf((v.z - mu) * rs);
        unsigned int h3 = f2bf((v.w - mu) * rs);
        uint2 pk;
        pk.x = h0 | (h1 << 16);
        pk.y = h2 | (h3 << 16);
        *(uint2*)&xsh[(w * 16 + it) * 264 + lane * 4] = pk;
    }
    __syncthreads();

    int l15 = lane & 15, q = lane >> 4;
    f32x4 acc[4];
#pragma unroll
    for (int nt = 0; nt < 4; ++nt) acc[nt] = (f32x4){0.f, 0.f, 0.f, 0.f};

    for (int k0 = 0; k0 < 256; k0 += 32) {
        bf16x8 a = *(bf16x8*)&xsh[(w * 16 + l15) * 264 + k0 + q * 8];
#pragma unroll
        for (int nt = 0; nt < 4; ++nt) {
            bf16x8 b = *(bf16x8*)&wpT[(nt * 16 + l15) * 264 + k0 + q * 8];
            acc[nt] = MFMA16(a, b, acc[nt]);
        }
    }

    float mval[4];
#pragma unroll
    for (int reg = 0; reg < 4; ++reg)
        mval[reg] = mask[(size_t)(s0 + w * 16 + q * 4 + reg) * I_DIM + i];

    __syncthreads();
    unsigned short* trsh = xsh;

#pragma unroll
    for (int nt = 0; nt < 4; ++nt) {
        int f = nt * 16 + l15;
        float bv = bias[f];
        unsigned int lo = (unsigned int)f2bf((acc[nt][0] + bv) * mval[0]) |
                          ((unsigned int)f2bf((acc[nt][1] + bv) * mval[1]) << 16);
        unsigned int hi = (unsigned int)f2bf((acc[nt][2] + bv) * mval[2]) |
                          ((unsigned int)f2bf((acc[nt][3] + bv) * mval[3]) << 16);
        uint2 pk; pk.x = lo; pk.y = hi;
        *(uint2*)&trsh[f * 72 + w * 16 + q * 4] = pk;
    }
    __syncthreads();

    {
        int fr = t >> 2, so = (t & 3) * 16;
        unsigned short* dst = ((fr < 32) ? lT : rT) + ((size_t)(i * 32 + (fr & 31)) * 128 + s0 + so);
        *(uint4*)dst = *(uint4*)&trsh[fr * 72 + so];
        *(uint4*)(dst + 8) = *(uint4*)&trsh[fr * 72 + so + 8];
    }
}

// ---------------- kernel A: outer GEMM -> Gp[pair][k] bf16 (slab-local) ----
// grid (96, slab_i/4). G stored pair-major in LDS: sh2[pair][e*32+d], pitch 1032.
__global__ __launch_bounds__(256, 4) void outer_kernel(const unsigned short* __restrict__ lT,
                                                       const unsigned short* __restrict__ rT,
                                                       unsigned short* __restrict__ Gp,
                                                       int ib0) {
    __shared__ unsigned short sh[128 * 136];   // r-tile, then reused as sh2[16][1032]
    int t = threadIdx.x;
    int bx = blockIdx.x, by = blockIdx.y;
    int colL0 = (ib0 + by) * 128, colR0 = bx * 128;
    int w = t >> 6, lane = t & 63, l15 = lane & 15, q = lane >> 4;

    const unsigned short* lbase = lT + (size_t)(colL0 + w * 32 + l15) * 128 + q * 8;
    bf16x8 a0 = *(const bf16x8*)(lbase);
    bf16x8 a1 = *(const bf16x8*)(lbase + 16 * 128);

    {
        int m0 = t >> 3, c0 = (t & 7) * 8;
        const unsigned short* rbase = rT + (size_t)(colR0 + m0) * 128 + c0;
#pragma unroll
        for (int p = 0; p < 4; ++p) {
            *(uint4*)&sh[(m0 + p * 32) * 136 + c0] = *(const uint4*)(rbase + (size_t)p * 32 * 128);
            *(uint4*)&sh[(m0 + p * 32) * 136 + c0 + 64] = *(const uint4*)(rbase + (size_t)p * 32 * 128 + 64);
        }
    }
    __syncthreads();

    f32x4 acc[2][8];
#pragma unroll
    for (int mt = 0; mt < 2; ++mt)
#pragma unroll
        for (int nt = 0; nt < 8; ++nt) acc[mt][nt] = (f32x4){0.f, 0.f, 0.f, 0.f};

#pragma unroll
    for (int k0 = 0; k0 < 4; ++k0) {
        bf16x8 na0 = a0, na1 = a1;
        if (k0 < 3) {
            na0 = *(const bf16x8*)(lbase + (k0 + 1) * 32);
            na1 = *(const bf16x8*)(lbase + 16 * 128 + (k0 + 1) * 32);
        }
#pragma unroll
        for (int nt = 0; nt < 8; ++nt) {
            bf16x8 b = *(bf16x8*)&sh[(nt * 16 + l15) * 136 + k0 * 32 + q * 8];
            acc[0][nt] = MFMA16(a0, b, acc[0][nt]);
            acc[1][nt] = MFMA16(a1, b, acc[1][nt]);
        }
        a0 = na0; a1 = na1;
    }
    __syncthreads();   // done reading r-tile

    // ---- write G pair-major: sh2[pair][e*32 + d], pitch 1032
#pragma unroll
    for (int mt = 0; mt < 2; ++mt) {
        int rowbase = w * 32 + mt * 16;       // multiple of 16
        int i_loc = rowbase >> 5;
        int d = (rowbase & 31) + q * 4;       // rows d..d+3 in regs
#pragma unroll
        for (int nt = 0; nt < 8; ++nt) {
            int col = nt * 16 + l15;
            int j_loc = col >> 5, e = col & 31;
            int pair = i_loc * 4 + j_loc;
            unsigned int lo = (unsigned int)f2bf(acc[mt][nt][0]) | ((unsigned int)f2bf(acc[mt][nt][1]) << 16);
            unsigned int hi = (unsigned int)f2bf(acc[mt][nt][2]) | ((unsigned int)f2bf(acc[mt][nt][3]) << 16);
            uint2 pk; pk.x = lo; pk.y = hi;
            *(uint2*)&sh[pair * 1032 + e * 32 + d] = pk;
        }
    }
    __syncthreads();

    // ---- Gp copy-out: straight rows, conflict-free b128, coalesced global
#pragma unroll
    for (int p8 = 0; p8 < 8; ++p8) {
        int g = p8 * 256 + t;
        int pair_loc = g >> 7;            // 0..15
        int c16 = g & 127;                // 16-B chunk in 2-KB row
        uint4 v = *(uint4*)&sh[pair_loc * 1032 + c16 * 8];
        size_t row = (size_t)(by * 4 + (pair_loc >> 2)) * I_DIM + bx * 4 + (pair_loc & 3);
        *(uint4*)&Gp[row * 1024 + (size_t)c16 * 8] = v;
    }
}

// ---------------- kernel B: out[pair][f] = Gp[pair][:] . W2 -- LDS-free, barrier-free
// grid = pairs_slab/64, 256 thr. A direct from Gp (L1-shared), B from W2s (coalesced).
__global__ __launch_bounds__(256, 4) void contract_kernel(const unsigned short* __restrict__ Gp,
                                                          const unsigned short* __restrict__ W2s,
                                                          const float* __restrict__ invn,
                                                          const float* __restrict__ out_bias,
                                                          float* __restrict__ out,
                                                          int pair0) {
    int t = threadIdx.x;
    int w = t >> 6, lane = t & 63, l15 = lane & 15, q = lane >> 4;
    size_t p0 = (size_t)blockIdx.x * 64;

    const unsigned short* a_base = Gp + (p0 + l15) * 1024 + q * 8;      // + mt*16384 + k0*32
    const unsigned short* w_base = W2s + (w * 32 + l15) * 32 + q * 8;   // + u*512 + k0*4096

    f32x4 acc[4][2];
#pragma unroll
    for (int mt = 0; mt < 4; ++mt) {
        acc[mt][0] = (f32x4){0.f, 0.f, 0.f, 0.f};
        acc[mt][1] = (f32x4){0.f, 0.f, 0.f, 0.f};
    }

    bf16x8 aC[4], aN[4], bC[2], bN[2];
#pragma unroll
    for (int mt = 0; mt < 4; ++mt) {
        aC[mt] = *(const bf16x8*)(a_base + mt * 16384);
        aN[mt] = *(const bf16x8*)(a_base + mt * 16384 + 32);
    }
    bC[0] = *(const bf16x8*)(w_base);
    bC[1] = *(const bf16x8*)(w_base + 512);
    bN[0] = *(const bf16x8*)(w_base + 4096);
    bN[1] = *(const bf16x8*)(w_base + 4096 + 512);

    for (int k0 = 0; k0 < 32; ++k0) {
        bf16x8 aP[4], bP[2];
#pragma unroll
        for (int mt = 0; mt < 4; ++mt) aP[mt] = aN[mt];
        bP[0] = bN[0]; bP[1] = bN[1];
        if (k0 + 2 < 32) {
            int off = (k0 + 2) * 32;
#pragma unroll
            for (int mt = 0; mt < 4; ++mt)
                aP[mt] = *(const bf16x8*)(a_base + mt * 16384 + off);
            bP[0] = *(const bf16x8*)(w_base + (size_t)(k0 + 2) * 4096);
            bP[1] = *(const bf16x8*)(w_base + (size_t)(k0 + 2) * 4096 + 512);
        }
#pragma unroll
        for (int mt = 0; mt < 4; ++mt) {
            acc[mt][0] = MFMA16(aC[mt], bC[0], acc[mt][0]);
            acc[mt][1] = MFMA16(aC[mt], bC[1], acc[mt][1]);
        }
#pragma unroll
        for (int mt = 0; mt < 4; ++mt) { aC[mt] = aN[mt]; aN[mt] = aP[mt]; }
        bC[0] = bN[0]; bC[1] = bN[1];
        bN[0] = bP[0]; bN[1] = bP[1];
    }

#pragma unroll
    for (int u = 0; u < 2; ++u) {
        int f = w * 32 + u * 16 + l15;
        float bv = out_bias[f];
#pragma unroll
        for (int mt = 0; mt < 4; ++mt) {
#pragma unroll
            for (int reg = 0; reg < 4; ++reg) {
                size_t pl = (size_t)pair0 + p0 + mt * 16 + q * 4 + reg;
                out[pl * 128 + f] = (acc[mt][u][reg] + bv) * invn[pl];
            }
        }
    }
}

extern "C" void kernel_launch(void* const* d_in, const int* in_sizes, int n_in,
                              void* d_out, int out_size, void* d_ws, size_t ws_size,
                              hipStream_t stream) {
    const float* node = (const float*)d_in[0];
    const float* mask = (const float*)d_in[1];
    const float* Wp   = (const float*)d_in[2];
    const float* bp   = (const float*)d_in[3];
    const float* W2   = (const float*)d_in[4];
    const float* bo   = (const float*)d_in[5];
    float* out = (float*)d_out;

    char* ws = (char*)d_ws;
    unsigned short* lT  = (unsigned short*)(ws);             // 3,145,728
    unsigned short* rT  = (unsigned short*)(ws + 3145728);   // 3,145,728
    unsigned short* W2s = (unsigned short*)(ws + 6291456);   // 262,144
    unsigned short* WpT = (unsigned short*)(ws + 6553600);   // 32,768
    float*          inv = (float*)(ws + 6586368);            // 589,824
    unsigned short* Gp  = (unsigned short*)(ws + 8388608);   // slab buffer

    // largest slab (i-values) fitting ws: 192 -> Gp 151 MB (L3-resident)
    int slab_i = 192;
    while (slab_i > 12 && 8388608ull + (size_t)slab_i * 384 * 1024 * 2 > ws_size) slab_i >>= 1;
    int nslab = 384 / slab_i;

    hipLaunchKernelGGL(prep_cast, dim3(512), dim3(256), 0, stream, Wp, W2, WpT, W2s);
    hipLaunchKernelGGL(norm_kernel, dim3(24, 24), dim3(256), 0, stream, mask, inv);
    hipLaunchKernelGGL(ln_proj, dim3(768), dim3(256), 0, stream, node, mask, bp, WpT, lT, rT);

    for (int s = 0; s < nslab; ++s) {
        hipLaunchKernelGGL(outer_kernel, dim3(96, slab_i / 4), dim3(256), 0, stream,
                           lT, rT, Gp, s * (slab_i / 4));
        hipLaunchKernelGGL(contract_kernel, dim3(slab_i * 6), dim3(256), 0, stream,
                           Gp, W2s, inv, bo, out, s * slab_i * I_DIM);
    }
}